// Round 4
// baseline (91.258 us; speedup 1.0000x reference)
//
#include <hip/hip_runtime.h>
#include <math.h>

typedef short short8 __attribute__((ext_vector_type(8)));
typedef float f32x4 __attribute__((ext_vector_type(4)));

#define B_N 2048
#define NKM 9
#define CP 512          // C*4
#define KU 128          // MUL
#define NG 28
#define NGA 7
#define PI_D 3.14159265358979323846
#define INV_SQRT_MUL 0.08838834764831845f   // 1/sqrt(128)
#define INV_SQRT_4C  0.04419417382415922f   // 1/sqrt(512)

// persistent device scratch; fully rewritten every launch before any read
__device__ ushort g_xb1[NKM * B_N * KU];          // [km][b][u] bf16
__device__ ushort g_xb2[NKM * B_N * KU];
__device__ ushort g_W1bt[3 * CP * KU];            // [l][cp][u] bf16, * 1/sqrt(128)
__device__ ushort g_W2bt[3 * CP * KU];
__device__ ushort g_Woutbt[3 * KU * CP];          // [l][u][cp] bf16, * 1/sqrt(512)
__device__ ushort g_c1b[(size_t)B_N * NKM * CP];  // [b][km][cp] bf16
__device__ ushort g_c2b[(size_t)B_N * NKM * CP];
__device__ ushort g_cb[(size_t)B_N * NKM * CP];   // c_out, bf16
__device__ float  g_G[729];                       // Gaunt tensor [k][i][j]

__device__ __forceinline__ ushort f2b(float f) {
    uint u = __float_as_uint(f);
    uint r = (u + 0x7fffu + ((u >> 16) & 1u)) >> 16;   // RNE
    return (ushort)r;
}
__device__ __forceinline__ float b2f(ushort h) {
    return __uint_as_float(((uint)h) << 16);
}
__device__ __forceinline__ int l_of_km(int km) { return (km >= 4) ? 2 : (km >= 1 ? 1 : 0); }

// compile-time Gaunt nonzero superset: l-parity, triangle, even #sin, |m| match
__host__ __device__ constexpr int lof(int n) { return n >= 4 ? 2 : (n >= 1 ? 1 : 0); }
__host__ __device__ constexpr int mof(int n) { int l = lof(n); return n - l * l - l; }
__host__ __device__ constexpr bool gaunt_nz(int a, int b, int c) {
    int la = lof(a), lb = lof(b), lc = lof(c);
    if ((la + lb + lc) & 1) return false;
    if (lc > la + lb || la > lb + lc || lb > lc + la) return false;
    int ma = mof(a), mb = mof(b), mc = mof(c);
    int neg = (ma < 0) + (mb < 0) + (mc < 0);
    if (neg & 1) return false;
    int A = ma < 0 ? -ma : ma, Bm = mb < 0 ? -mb : mb, Cm = mc < 0 ? -mc : mc;
    return (A + Bm == Cm) || (Bm + Cm == A) || (Cm + A == Bm);
}

// ---------------------------------------------------------------------------
// prep_small: W converts (blocks 0..767) + SH basis -> Gaunt tensor (block 768)
// ---------------------------------------------------------------------------
__global__ void prep_small_kernel(const float* __restrict__ W1, const float* __restrict__ W2,
                                  const float* __restrict__ Wout) {
    __shared__ float Ys[9 * NG];
    __shared__ float qws[NG];
    int bid = blockIdx.x;
    if (bid == 768) {
        int g = threadIdx.x;
        if (g < NG) {
            int ib = g / NGA, ia = g - ib * NGA;
            const double xs[4] = {-0.8611363115940526, -0.3399810435848563,
                                   0.3399810435848563,  0.8611363115940526};
            const double ws[4] = { 0.3478548451374538,  0.6521451548625461,
                                   0.6521451548625461,  0.3478548451374538};
            double x = xs[ib], w = ws[ib];
            double s = sqrt(1.0 - x * x);
            double alpha = 2.0 * PI_D * (double)ia / (double)NGA;
            double P00 = sqrt(1.0 / (4.0 * PI_D));
            double P11 = -sqrt(3.0 / 2.0) * s * P00;
            double P22 = -sqrt(5.0 / 4.0) * s * P11;
            double P10 = sqrt(3.0) * x * P00;
            double P21 = sqrt(5.0) * x * P11;
            double P20 = sqrt(15.0 / 4.0) * (x * P10 - sqrt(1.0 / 3.0) * P00);
            double r2 = sqrt(2.0);
            double Y[9];
            Y[0] = P00;
            Y[1] = r2 * P11 * sin(alpha);
            Y[2] = P10;
            Y[3] = r2 * P11 * cos(alpha);
            Y[4] = r2 * P22 * sin(2.0 * alpha);
            Y[5] = r2 * P21 * sin(alpha);
            Y[6] = P20;
            Y[7] = r2 * P21 * cos(alpha);
            Y[8] = r2 * P22 * cos(2.0 * alpha);
            for (int k = 0; k < 9; ++k) Ys[k * NG + g] = (float)Y[k];
            qws[g] = (float)(w * (2.0 * PI_D / (double)NGA));
        }
        __syncthreads();
        for (int e = threadIdx.x; e < 729; e += 256) {
            int kk = e / 81, rem = e - kk * 81, i = rem / 9, j = rem - i * 9;
            float s = 0.f;
            for (int g2 = 0; g2 < NG; ++g2)
                s += Ys[kk * NG + g2] * Ys[i * NG + g2] * Ys[j * NG + g2] * qws[g2];
            g_G[e] = s;
        }
        return;
    }
    int idx = bid * 256 + threadIdx.x;       // < 3*512*128 = 196608
    int l = idx >> 16;
    int r = idx & 65535;
    {   // W1bt/W2bt [l][cp][u]  <-  W[l][u][cp] * 1/sqrt(128)
        int cp = r >> 7, u = r & 127;
        g_W1bt[idx] = f2b(W1[(size_t)l * 65536 + (size_t)u * 512 + cp] * INV_SQRT_MUL);
        g_W2bt[idx] = f2b(W2[(size_t)l * 65536 + (size_t)u * 512 + cp] * INV_SQRT_MUL);
    }
    {   // Woutbt [l][u][cp]  <-  Wout[l][cp][u] * 1/sqrt(512)
        int u = r >> 9, cp = r & 511;
        g_Woutbt[idx] = f2b(Wout[(size_t)l * 65536 + (size_t)cp * 128 + u] * INV_SQRT_4C);
    }
}

// ---------------------------------------------------------------------------
// prep_x: x [B,2048] fp32 -> xb [km][B][u] bf16 (m-major, K-contiguous)
// ---------------------------------------------------------------------------
__global__ void prep_x_kernel(const float* __restrict__ x1, const float* __restrict__ x2) {
    int idx = blockIdx.x * 256 + threadIdx.x;   // < 9*2048*128
    int km = idx >> 18;
    int b  = (idx >> 7) & 2047;
    int u  = idx & 127;
    int l = l_of_km(km);
    int mi = km - l * l;
    int col = l * l * 128 + u * (2 * l + 1) + mi;
    g_xb1[idx] = f2b(x1[(size_t)b * 2048 + col]);
    g_xb2[idx] = f2b(x2[(size_t)b * 2048 + col]);
}

// ---------------------------------------------------------------------------
// zero_tail: out columns [1152, 2048) = l=3 zero block
// ---------------------------------------------------------------------------
__global__ void zero_tail_kernel(float* __restrict__ out) {
    int idx = blockIdx.x * 256 + threadIdx.x;   // < 2048*224
    int b = idx / 224, q = idx - b * 224;
    *(float4*)&out[(size_t)b * 2048 + 1152 + q * 4] = make_float4(0.f, 0.f, 0.f, 0.f);
}

// ---------------------------------------------------------------------------
// gemm_c: c[b][km][cp] = sum_u xb[km][b][u] * Wbt[l][cp][u]   (bf16 out)
// grid (32 m-tiles, 8 n-tiles, 18 = field*9+km), 64x64 tile, K=128 resident
// ---------------------------------------------------------------------------
__global__ __launch_bounds__(256) void gemm_c_kernel() {
    __shared__ ushort As[64 * 128];
    __shared__ ushort Bs[64 * 128];
    int tid = threadIdx.x;
    int z = blockIdx.z;
    int field = (z >= NKM);
    int km = field ? z - NKM : z;
    int l = l_of_km(km);
    int b0 = blockIdx.x * 64, n0 = blockIdx.y * 64;
    const ushort* xa = (field ? g_xb2 : g_xb1) + (size_t)km * (B_N * KU);
    const ushort* wb = (field ? g_W2bt : g_W1bt) + (size_t)l * 65536;
    ushort* cdst = field ? g_c2b : g_c1b;

    #pragma unroll
    for (int it = 0; it < 4; ++it) {
        int i = it * 256 + tid;            // 16B chunk id, 0..1023
        int row = i >> 4, kg = i & 15;
        int dst = row * 128 + ((kg ^ (row & 7)) << 3);
        *(short8*)&As[dst] = *(const short8*)&xa[(size_t)(b0 + row) * KU + (kg << 3)];
        *(short8*)&Bs[dst] = *(const short8*)&wb[(size_t)(n0 + row) * KU + (kg << 3)];
    }
    __syncthreads();

    int lane = tid & 63, wid = tid >> 6, wr = wid >> 1, wc = wid & 1;
    f32x4 acc[2][2];
    #pragma unroll
    for (int i = 0; i < 2; ++i)
        #pragma unroll
        for (int j = 0; j < 2; ++j) acc[i][j] = (f32x4){0.f, 0.f, 0.f, 0.f};

    #pragma unroll
    for (int ks = 0; ks < 4; ++ks) {
        int kg = ks * 4 + (lane >> 4);
        short8 a[2], b[2];
        #pragma unroll
        for (int i = 0; i < 2; ++i) {
            int row = wr * 32 + i * 16 + (lane & 15);
            a[i] = *(const short8*)&As[row * 128 + ((kg ^ (row & 7)) << 3)];
        }
        #pragma unroll
        for (int j = 0; j < 2; ++j) {
            int row = wc * 32 + j * 16 + (lane & 15);
            b[j] = *(const short8*)&Bs[row * 128 + ((kg ^ (row & 7)) << 3)];
        }
        #pragma unroll
        for (int i = 0; i < 2; ++i)
            #pragma unroll
            for (int j = 0; j < 2; ++j)
                acc[i][j] = __builtin_amdgcn_mfma_f32_16x16x32_bf16(a[i], b[j], acc[i][j], 0, 0, 0);
    }

    #pragma unroll
    for (int i = 0; i < 2; ++i)
        #pragma unroll
        for (int j = 0; j < 2; ++j)
            #pragma unroll
            for (int r = 0; r < 4; ++r) {
                int row = b0 + wr * 32 + i * 16 + ((lane >> 4) << 2) + r;
                int col = n0 + wc * 32 + j * 16 + (lane & 15);
                cdst[((size_t)row * NKM + km) * CP + col] = f2b(acc[i][j][r]);
            }
}

// ---------------------------------------------------------------------------
// middle: Gaunt-sparse bilinear contraction per (b,c); 83 compile-time entries
// ---------------------------------------------------------------------------
__global__ __launch_bounds__(256) void middle_kernel() {
    __shared__ float Gs[729];
    int tid = threadIdx.x;
    for (int i = tid; i < 729; i += 256) Gs[i] = g_G[i];
    __syncthreads();

    int idx = blockIdx.x * 256 + tid;
    int b = idx >> 7, c = idx & 127;

    float c1[4][9], c2[4][9];
    #pragma unroll
    for (int k = 0; k < 9; ++k) {
        ushort4 v1 = *(const ushort4*)&g_c1b[((size_t)b * NKM + k) * CP + c * 4];
        ushort4 v2 = *(const ushort4*)&g_c2b[((size_t)b * NKM + k) * CP + c * 4];
        c1[0][k] = b2f(v1.x); c1[1][k] = b2f(v1.y); c1[2][k] = b2f(v1.z); c1[3][k] = b2f(v1.w);
        c2[0][k] = b2f(v2.x); c2[1][k] = b2f(v2.y); c2[2][k] = b2f(v2.z); c2[3][k] = b2f(v2.w);
    }

    float o[4][9];
    #pragma unroll
    for (int p = 0; p < 4; ++p)
        #pragma unroll
        for (int k = 0; k < 9; ++k) o[p][k] = 0.f;

    #pragma unroll
    for (int kk = 0; kk < 9; ++kk) {
        #pragma unroll
        for (int i = 0; i < 9; ++i) {
            #pragma unroll
            for (int j = 0; j < 9; ++j) {
                if (gaunt_nz(kk, i, j)) {          // compile-time predicate (83 hits)
                    float g = Gs[(kk * 9 + i) * 9 + j];
                    o[0][kk] = fmaf(g, c1[0][i] * c2[0][j], o[0][kk]);
                    float x1 = fmaf(c1[2][i], c2[3][j], -(c1[3][i] * c2[2][j]));
                    float x2 = fmaf(c1[3][i], c2[1][j], -(c1[1][i] * c2[3][j]));
                    float x3 = fmaf(c1[1][i], c2[2][j], -(c1[2][i] * c2[1][j]));
                    o[1][kk] = fmaf(g, x1, o[1][kk]);
                    o[2][kk] = fmaf(g, x2, o[2][kk]);
                    o[3][kk] = fmaf(g, x3, o[3][kk]);
                }
            }
        }
    }

    #pragma unroll
    for (int k = 0; k < 9; ++k) {
        ushort4 v;
        v.x = f2b(o[0][k]); v.y = f2b(o[1][k]); v.z = f2b(o[2][k]); v.w = f2b(o[3][k]);
        *(ushort4*)&g_cb[((size_t)b * NKM + k) * CP + c * 4] = v;
    }
}

// ---------------------------------------------------------------------------
// out_gemm: out[b][OFF_l + u*d + mi] = sum_cp c_out[b][km][cp] * Woutb[l][cp][u]
// grid (32 m-tiles, 2 n-tiles, 9 km), 64x64 tile, K=512 in 4 chunks
// ---------------------------------------------------------------------------
__global__ __launch_bounds__(256) void out_gemm_kernel(float* __restrict__ out) {
    __shared__ ushort As[64 * 128];
    __shared__ ushort Bs[64 * 128];
    int tid = threadIdx.x;
    int km = blockIdx.z;
    int l = l_of_km(km);
    int mi = km - l * l, d = 2 * l + 1, OFF = 128 * l * l;
    int b0 = blockIdx.x * 64, u0 = blockIdx.y * 64;

    int lane = tid & 63, wid = tid >> 6, wr = wid >> 1, wc = wid & 1;
    f32x4 acc[2][2];
    #pragma unroll
    for (int i = 0; i < 2; ++i)
        #pragma unroll
        for (int j = 0; j < 2; ++j) acc[i][j] = (f32x4){0.f, 0.f, 0.f, 0.f};

    for (int kc = 0; kc < 4; ++kc) {
        #pragma unroll
        for (int it = 0; it < 4; ++it) {
            int i = it * 256 + tid;
            int row = i >> 4, kg = i & 15;
            int dst = row * 128 + ((kg ^ (row & 7)) << 3);
            *(short8*)&As[dst] = *(const short8*)&g_cb[(size_t)(b0 + row) * (NKM * CP)
                                                       + (size_t)km * CP + kc * 128 + (kg << 3)];
            *(short8*)&Bs[dst] = *(const short8*)&g_Woutbt[(size_t)l * 65536
                                                       + (size_t)(u0 + row) * CP + kc * 128 + (kg << 3)];
        }
        __syncthreads();
        #pragma unroll
        for (int ks = 0; ks < 4; ++ks) {
            int kg = ks * 4 + (lane >> 4);
            short8 a[2], b[2];
            #pragma unroll
            for (int i = 0; i < 2; ++i) {
                int row = wr * 32 + i * 16 + (lane & 15);
                a[i] = *(const short8*)&As[row * 128 + ((kg ^ (row & 7)) << 3)];
            }
            #pragma unroll
            for (int j = 0; j < 2; ++j) {
                int row = wc * 32 + j * 16 + (lane & 15);
                b[j] = *(const short8*)&Bs[row * 128 + ((kg ^ (row & 7)) << 3)];
            }
            #pragma unroll
            for (int i = 0; i < 2; ++i)
                #pragma unroll
                for (int j = 0; j < 2; ++j)
                    acc[i][j] = __builtin_amdgcn_mfma_f32_16x16x32_bf16(a[i], b[j], acc[i][j], 0, 0, 0);
        }
        __syncthreads();
    }

    #pragma unroll
    for (int i = 0; i < 2; ++i)
        #pragma unroll
        for (int j = 0; j < 2; ++j)
            #pragma unroll
            for (int r = 0; r < 4; ++r) {
                int row = b0 + wr * 32 + i * 16 + ((lane >> 4) << 2) + r;
                int u   = u0 + wc * 32 + j * 16 + (lane & 15);
                out[(size_t)row * 2048 + OFF + u * d + mi] = acc[i][j][r];
            }
}

// ---------------------------------------------------------------------------
extern "C" void kernel_launch(void* const* d_in, const int* in_sizes, int n_in,
                              void* d_out, int out_size, void* d_ws, size_t ws_size,
                              hipStream_t stream) {
    const float* x1   = (const float*)d_in[0];
    const float* x2   = (const float*)d_in[1];
    const float* W1   = (const float*)d_in[2];
    const float* W2   = (const float*)d_in[3];
    const float* Wout = (const float*)d_in[4];
    float* out = (float*)d_out;

    zero_tail_kernel<<<1792, 256, 0, stream>>>(out);
    prep_small_kernel<<<769, 256, 0, stream>>>(W1, W2, Wout);
    prep_x_kernel<<<9216, 256, 0, stream>>>(x1, x2);

    gemm_c_kernel<<<dim3(B_N / 64, CP / 64, 18), 256, 0, stream>>>();
    middle_kernel<<<(B_N * 128) / 256, 256, 0, stream>>>();
    out_gemm_kernel<<<dim3(B_N / 64, 128 / 64, NKM), 256, 0, stream>>>(out);
}